// Round 2
// baseline (59.339 us; speedup 1.0000x reference)
//
#include <hip/hip_runtime.h>
#include <math.h>

// Banded self-attention, fp32. B=4, T=4096, D=64, MASK_NUM=64.
// One 64-lane wave per query row. 8 subgroups of 8 lanes; subgroup g handles
// keys s = s_lo+g, s_lo+g+8, ... (17 slots cover the <=129-key band).
// Lane r of a subgroup owns dims [8r, 8r+8).
// Scores for the whole band are held in registers (p[17]) -> softmax is
// batched (one max pass, 17 independent exps), no online rescaling.

constexpr int kB = 4;
constexpr int kT = 4096;
constexpr int kD = 64;
constexpr int kBand = 64;   // MASK_NUM
constexpr int kIters = 17;  // ceil(129/8)

__global__ __launch_bounds__(256, 4) void band_attn_kernel(
    const float* __restrict__ Q,
    const float* __restrict__ K,
    const float* __restrict__ V,
    const int*   __restrict__ M,
    float* __restrict__ O)
{
    const int lane = threadIdx.x & 63;
    const int wid  = threadIdx.x >> 6;
    const int row  = (blockIdx.x << 2) + wid;     // row = b*T + t
    if (row >= kB * kT) return;
    const int b = row >> 12;
    const int t = row & (kT - 1);

    const int g = lane >> 3;   // subgroup 0..7 (key slot)
    const int r = lane & 7;    // dims 8r..8r+7

    const float* qr = Q + (size_t)row * kD + 8 * r;
    float4 q0 = *reinterpret_cast<const float4*>(qr);
    float4 q1 = *reinterpret_cast<const float4*>(qr + 4);
    // fold 1/sqrt(D) into Q
    q0.x *= 0.125f; q0.y *= 0.125f; q0.z *= 0.125f; q0.w *= 0.125f;
    q1.x *= 0.125f; q1.y *= 0.125f; q1.z *= 0.125f; q1.w *= 0.125f;

    const float* kb = K + (size_t)b * kT * kD;
    const float* vb = V + (size_t)b * kT * kD;
    const int*   mb = M + b * kT;
    const int qm = mb[t];

    float4 acc0 = make_float4(0.f, 0.f, 0.f, 0.f);
    float4 acc1 = make_float4(0.f, 0.f, 0.f, 0.f);
    float  l = 0.0f;

    if (qm) {
        // allowed(s) = band(t,s) && mask[b,s]
        int s_lo = t - kBand; if (s_lo < 0) s_lo = 0;
        int s_hi = t + kBand; if (s_hi > kT - 1) s_hi = kT - 1;
        const int s0 = s_lo + g;

        // ---- phase 1: all scores into registers ----
        float p[kIters];
        #pragma unroll
        for (int i = 0; i < kIters; ++i) {
            const int s  = s0 + 8 * i;
            const bool in = (s <= s_hi);
            const int sc = in ? s : s_hi;          // clamped (safe) address
            const float* kr = kb + (size_t)sc * kD + 8 * r;
            const float4 k0 = *reinterpret_cast<const float4*>(kr);
            const float4 k1 = *reinterpret_cast<const float4*>(kr + 4);
            float d = q0.x * k0.x + q0.y * k0.y + q0.z * k0.z + q0.w * k0.w
                    + q1.x * k1.x + q1.y * k1.y + q1.z * k1.z + q1.w * k1.w;
            d += __shfl_xor(d, 1, 64);
            d += __shfl_xor(d, 2, 64);
            d += __shfl_xor(d, 4, 64);
            p[i] = (in && mb[sc]) ? d : -INFINITY;
        }

        // ---- phase 2: row max (batched) ----
        float mx = p[0];
        #pragma unroll
        for (int i = 1; i < kIters; ++i) mx = fmaxf(mx, p[i]);
        mx = fmaxf(mx, __shfl_xor(mx, 8, 64));
        mx = fmaxf(mx, __shfl_xor(mx, 16, 64));
        mx = fmaxf(mx, __shfl_xor(mx, 32, 64));
        // qm==1 => s=t allowed => mx finite

        // ---- phase 3: exp + sum + PV (independent per key) ----
        #pragma unroll
        for (int i = 0; i < kIters; ++i) {
            const int s  = s0 + 8 * i;
            const int sc = (s <= s_hi) ? s : s_hi;
            const float w = __expf(p[i] - mx);     // exp(-inf)=0 for masked
            l += w;
            const float* vr = vb + (size_t)sc * kD + 8 * r;
            const float4 v0 = *reinterpret_cast<const float4*>(vr);
            const float4 v1 = *reinterpret_cast<const float4*>(vr + 4);
            acc0.x += w * v0.x; acc0.y += w * v0.y;
            acc0.z += w * v0.z; acc0.w += w * v0.w;
            acc1.x += w * v1.x; acc1.y += w * v1.y;
            acc1.z += w * v1.z; acc1.w += w * v1.w;
        }
    } else {
        // Fallback (wave-uniform branch, not hit by the bench mask):
        // attend to every s with mask[b,s]==1; online softmax.
        float m = -INFINITY;
        for (int s = g; s < kT; s += 8) {
            const float* kr = kb + (size_t)s * kD + 8 * r;
            const float4 k0 = *reinterpret_cast<const float4*>(kr);
            const float4 k1 = *reinterpret_cast<const float4*>(kr + 4);
            float d = q0.x * k0.x + q0.y * k0.y + q0.z * k0.z + q0.w * k0.w
                    + q1.x * k1.x + q1.y * k1.y + q1.z * k1.z + q1.w * k1.w;
            d += __shfl_xor(d, 1, 64);
            d += __shfl_xor(d, 2, 64);
            d += __shfl_xor(d, 4, 64);
            if (mb[s]) {
                const float mn  = fmaxf(m, d);
                const float scl = __expf(m - mn);
                const float w   = __expf(d - mn);
                const float* vr = vb + (size_t)s * kD + 8 * r;
                const float4 v0 = *reinterpret_cast<const float4*>(vr);
                const float4 v1 = *reinterpret_cast<const float4*>(vr + 4);
                l = l * scl + w;
                acc0.x = acc0.x * scl + w * v0.x; acc0.y = acc0.y * scl + w * v0.y;
                acc0.z = acc0.z * scl + w * v0.z; acc0.w = acc0.w * scl + w * v0.w;
                acc1.x = acc1.x * scl + w * v1.x; acc1.y = acc1.y * scl + w * v1.y;
                acc1.z = acc1.z * scl + w * v1.z; acc1.w = acc1.w * scl + w * v1.w;
                m = mn;
            }
        }
        // merge subgroup maxima before the shared butterfly below:
        #pragma unroll
        for (int off = 8; off <= 32; off <<= 1) {
            const float m2 = __shfl_xor(m, off, 64);
            const float l2 = __shfl_xor(l, off, 64);
            float4 b0, b1;
            b0.x = __shfl_xor(acc0.x, off, 64); b0.y = __shfl_xor(acc0.y, off, 64);
            b0.z = __shfl_xor(acc0.z, off, 64); b0.w = __shfl_xor(acc0.w, off, 64);
            b1.x = __shfl_xor(acc1.x, off, 64); b1.y = __shfl_xor(acc1.y, off, 64);
            b1.z = __shfl_xor(acc1.z, off, 64); b1.w = __shfl_xor(acc1.w, off, 64);
            const float mm = fmaxf(m, m2);
            const float e1 = __expf(m  - mm);
            const float e2 = __expf(m2 - mm);
            l = l * e1 + l2 * e2;
            acc0.x = acc0.x * e1 + b0.x * e2; acc0.y = acc0.y * e1 + b0.y * e2;
            acc0.z = acc0.z * e1 + b0.z * e2; acc0.w = acc0.w * e1 + b0.w * e2;
            acc1.x = acc1.x * e1 + b1.x * e2; acc1.y = acc1.y * e1 + b1.y * e2;
            acc1.z = acc1.z * e1 + b1.z * e2; acc1.w = acc1.w * e1 + b1.w * e2;
            m = mm;
        }
        if (g == 0) {
            const float inv = 1.0f / l;
            float* orow = O + (size_t)row * kD + 8 * r;
            float4 o0, o1;
            o0.x = acc0.x * inv; o0.y = acc0.y * inv;
            o0.z = acc0.z * inv; o0.w = acc0.w * inv;
            o1.x = acc1.x * inv; o1.y = acc1.y * inv;
            o1.z = acc1.z * inv; o1.w = acc1.w * inv;
            *reinterpret_cast<float4*>(orow)     = o0;
            *reinterpret_cast<float4*>(orow + 4) = o1;
        }
        return;
    }

    // ---- merge the 8 subgroup partial sums (main path) ----
    #pragma unroll
    for (int off = 8; off <= 32; off <<= 1) {
        l += __shfl_xor(l, off, 64);
        acc0.x += __shfl_xor(acc0.x, off, 64);
        acc0.y += __shfl_xor(acc0.y, off, 64);
        acc0.z += __shfl_xor(acc0.z, off, 64);
        acc0.w += __shfl_xor(acc0.w, off, 64);
        acc1.x += __shfl_xor(acc1.x, off, 64);
        acc1.y += __shfl_xor(acc1.y, off, 64);
        acc1.z += __shfl_xor(acc1.z, off, 64);
        acc1.w += __shfl_xor(acc1.w, off, 64);
    }

    if (g == 0) {
        const float inv = 1.0f / l;
        float* orow = O + (size_t)row * kD + 8 * r;
        float4 o0, o1;
        o0.x = acc0.x * inv; o0.y = acc0.y * inv;
        o0.z = acc0.z * inv; o0.w = acc0.w * inv;
        o1.x = acc1.x * inv; o1.y = acc1.y * inv;
        o1.z = acc1.z * inv; o1.w = acc1.w * inv;
        *reinterpret_cast<float4*>(orow)     = o0;
        *reinterpret_cast<float4*>(orow + 4) = o1;
    }
}

extern "C" void kernel_launch(void* const* d_in, const int* in_sizes, int n_in,
                              void* d_out, int out_size, void* d_ws, size_t ws_size,
                              hipStream_t stream) {
    const float* q    = (const float*)d_in[0];
    const float* k    = (const float*)d_in[1];
    const float* v    = (const float*)d_in[2];
    const int*   mask = (const int*)d_in[3];
    float*       out  = (float*)d_out;

    const int rows = kB * kT;                 // 16384 query rows
    dim3 grid((rows + 3) / 4);                // 4 waves (rows) per block
    dim3 block(256);
    band_attn_kernel<<<grid, block, 0, stream>>>(q, k, v, mask, out);
}

// Round 3
// 30.099 us; speedup vs baseline: 1.9714x; 1.9714x over previous
//
#include <hip/hip_runtime.h>
#include <math.h>

// Banded self-attention, fp32. B=4, T=4096, D=64, MASK_NUM=64.
// One 64-lane wave handles TWO consecutive query rows (t0, t0+1): their
// bands overlap in all but 2 keys, so each K/V row load feeds two dots.
// 8 subgroups of 8 lanes; subgroup g handles key slots s = s_lo+g+8i.
// Lane r of a subgroup owns dims [8r, 8r+8).
// Whole-band scores live in registers (p0/p1[18]) -> batched softmax.
// In-subgroup dot reduction uses DPP adds (pure VALU, no LDS pipe).
// K/V loads are issued in batches of 6 rows for memory-level parallelism.

constexpr int kB = 4;
constexpr int kT = 4096;
constexpr int kD = 64;
constexpr int kBand = 64;   // MASK_NUM
constexpr int kIters = 18;  // ceil(131/8) rounded to batch multiple
constexpr int kBatch = 6;

__device__ __forceinline__ float sum8_dpp(float x) {
    // all-lanes sum within each 8-lane half-row:
    // xor1 (quad_perm [1,0,3,2]=0xB1), xor2 (quad_perm [2,3,0,1]=0x4E),
    // then half-row mirror (0x141) to combine the two quads.
    int v = __float_as_int(x);
    x += __int_as_float(__builtin_amdgcn_update_dpp(0, v, 0xB1, 0xF, 0xF, true));
    v = __float_as_int(x);
    x += __int_as_float(__builtin_amdgcn_update_dpp(0, v, 0x4E, 0xF, 0xF, true));
    v = __float_as_int(x);
    x += __int_as_float(__builtin_amdgcn_update_dpp(0, v, 0x141, 0xF, 0xF, true));
    return x;
}

__global__ __launch_bounds__(256, 3) void band_attn_kernel(
    const float* __restrict__ Q,
    const float* __restrict__ K,
    const float* __restrict__ V,
    const int*   __restrict__ M,
    float* __restrict__ O)
{
    const int lane = threadIdx.x & 63;
    const int wid  = threadIdx.x >> 6;
    const int pid  = (blockIdx.x << 2) + wid;      // query-pair id
    if (pid >= (kB * kT) / 2) return;
    const int b  = pid >> 11;                      // 2048 pairs per batch
    const int t0 = (pid & 2047) << 1;
    const int t1 = t0 + 1;
    const int row0 = b * kT + t0;

    const int g = lane >> 3;   // subgroup 0..7 (key slot)
    const int r = lane & 7;    // dims 8r..8r+7

    const float* qra = Q + (size_t)row0 * kD + 8 * r;
    float4 qa0 = *reinterpret_cast<const float4*>(qra);
    float4 qa1 = *reinterpret_cast<const float4*>(qra + 4);
    float4 qb0 = *reinterpret_cast<const float4*>(qra + kD);
    float4 qb1 = *reinterpret_cast<const float4*>(qra + kD + 4);
    // fold 1/sqrt(D)=0.125 into Q
    qa0.x *= 0.125f; qa0.y *= 0.125f; qa0.z *= 0.125f; qa0.w *= 0.125f;
    qa1.x *= 0.125f; qa1.y *= 0.125f; qa1.z *= 0.125f; qa1.w *= 0.125f;
    qb0.x *= 0.125f; qb0.y *= 0.125f; qb0.z *= 0.125f; qb0.w *= 0.125f;
    qb1.x *= 0.125f; qb1.y *= 0.125f; qb1.z *= 0.125f; qb1.w *= 0.125f;

    const float* kb = K + (size_t)b * kT * kD;
    const float* vb = V + (size_t)b * kT * kD;
    const int*   mb = M + b * kT;

    const int qm0 = mb[t0];
    const int qm1 = mb[t1];

    if (qm0 && qm1) {
        // -------- fast path: both queries banded --------
        int s_lo = t0 - kBand; if (s_lo < 0) s_lo = 0;
        int s_hi = t1 + kBand; if (s_hi > kT - 1) s_hi = kT - 1;
        const int s0 = s_lo + g;
        const int hi0 = t0 + kBand;   // q0 upper band edge
        const int lo1 = t1 - kBand;   // q1 lower band edge

        // prefetch band mask bits (one bit per slot)
        unsigned mv = 0u;
        #pragma unroll
        for (int i = 0; i < kIters; ++i) {
            const int s  = s0 + 8 * i;
            const int sc = (s <= s_hi) ? s : s_hi;
            mv |= (mb[sc] ? 1u : 0u) << i;
        }

        // ---- phase 1: scores (batched K loads for MLP) ----
        float p0[kIters], p1[kIters];
        #pragma unroll
        for (int base = 0; base < kIters; base += kBatch) {
            float4 ka[kBatch], kc[kBatch];
            #pragma unroll
            for (int j = 0; j < kBatch; ++j) {
                const int s  = s0 + 8 * (base + j);
                const int sc = (s <= s_hi) ? s : s_hi;
                const float* kr = kb + (size_t)sc * kD + 8 * r;
                ka[j] = *reinterpret_cast<const float4*>(kr);
                kc[j] = *reinterpret_cast<const float4*>(kr + 4);
            }
            #pragma unroll
            for (int j = 0; j < kBatch; ++j) {
                const int i = base + j;
                const int s = s0 + 8 * i;
                float dA = qa0.x * ka[j].x + qa0.y * ka[j].y + qa0.z * ka[j].z + qa0.w * ka[j].w
                         + qa1.x * kc[j].x + qa1.y * kc[j].y + qa1.z * kc[j].z + qa1.w * kc[j].w;
                float dB = qb0.x * ka[j].x + qb0.y * ka[j].y + qb0.z * ka[j].z + qb0.w * ka[j].w
                         + qb1.x * kc[j].x + qb1.y * kc[j].y + qb1.z * kc[j].z + qb1.w * kc[j].w;
                dA = sum8_dpp(dA);
                dB = sum8_dpp(dB);
                const bool mk = (mv >> i) & 1u;
                const bool inr = (s <= s_hi);
                p0[i] = (inr && mk && s <= hi0) ? dA : -INFINITY;
                p1[i] = (inr && mk && s >= lo1) ? dB : -INFINITY;
            }
        }

        // ---- phase 2: row maxima ----
        float mx0 = p0[0], mx1 = p1[0];
        #pragma unroll
        for (int i = 1; i < kIters; ++i) {
            mx0 = fmaxf(mx0, p0[i]);
            mx1 = fmaxf(mx1, p1[i]);
        }
        #pragma unroll
        for (int off = 8; off <= 32; off <<= 1) {
            mx0 = fmaxf(mx0, __shfl_xor(mx0, off, 64));
            mx1 = fmaxf(mx1, __shfl_xor(mx1, off, 64));
        }

        // ---- phase 3: exp + sum + PV (batched V loads) ----
        float l0 = 0.f, l1 = 0.f;
        float4 a00 = make_float4(0.f,0.f,0.f,0.f), a01 = a00;
        float4 a10 = a00, a11 = a00;
        #pragma unroll
        for (int base = 0; base < kIters; base += kBatch) {
            float4 va[kBatch], vc[kBatch];
            #pragma unroll
            for (int j = 0; j < kBatch; ++j) {
                const int s  = s0 + 8 * (base + j);
                const int sc = (s <= s_hi) ? s : s_hi;
                const float* vr = vb + (size_t)sc * kD + 8 * r;
                va[j] = *reinterpret_cast<const float4*>(vr);
                vc[j] = *reinterpret_cast<const float4*>(vr + 4);
            }
            #pragma unroll
            for (int j = 0; j < kBatch; ++j) {
                const int i = base + j;
                const float w0 = __expf(p0[i] - mx0);   // exp(-inf)=0 for masked
                const float w1 = __expf(p1[i] - mx1);
                l0 += w0; l1 += w1;
                a00.x += w0 * va[j].x; a00.y += w0 * va[j].y;
                a00.z += w0 * va[j].z; a00.w += w0 * va[j].w;
                a01.x += w0 * vc[j].x; a01.y += w0 * vc[j].y;
                a01.z += w0 * vc[j].z; a01.w += w0 * vc[j].w;
                a10.x += w1 * va[j].x; a10.y += w1 * va[j].y;
                a10.z += w1 * va[j].z; a10.w += w1 * va[j].w;
                a11.x += w1 * vc[j].x; a11.y += w1 * vc[j].y;
                a11.z += w1 * vc[j].z; a11.w += w1 * vc[j].w;
            }
        }

        // ---- merge subgroup partials ----
        #pragma unroll
        for (int off = 8; off <= 32; off <<= 1) {
            l0 += __shfl_xor(l0, off, 64);
            l1 += __shfl_xor(l1, off, 64);
            a00.x += __shfl_xor(a00.x, off, 64); a00.y += __shfl_xor(a00.y, off, 64);
            a00.z += __shfl_xor(a00.z, off, 64); a00.w += __shfl_xor(a00.w, off, 64);
            a01.x += __shfl_xor(a01.x, off, 64); a01.y += __shfl_xor(a01.y, off, 64);
            a01.z += __shfl_xor(a01.z, off, 64); a01.w += __shfl_xor(a01.w, off, 64);
            a10.x += __shfl_xor(a10.x, off, 64); a10.y += __shfl_xor(a10.y, off, 64);
            a10.z += __shfl_xor(a10.z, off, 64); a10.w += __shfl_xor(a10.w, off, 64);
            a11.x += __shfl_xor(a11.x, off, 64); a11.y += __shfl_xor(a11.y, off, 64);
            a11.z += __shfl_xor(a11.z, off, 64); a11.w += __shfl_xor(a11.w, off, 64);
        }

        if (g == 0) {
            const float inv = 1.0f / l0;
            float* orow = O + (size_t)row0 * kD + 8 * r;
            float4 o0, o1;
            o0.x = a00.x * inv; o0.y = a00.y * inv; o0.z = a00.z * inv; o0.w = a00.w * inv;
            o1.x = a01.x * inv; o1.y = a01.y * inv; o1.z = a01.z * inv; o1.w = a01.w * inv;
            *reinterpret_cast<float4*>(orow)     = o0;
            *reinterpret_cast<float4*>(orow + 4) = o1;
        } else if (g == 1) {
            const float inv = 1.0f / l1;
            float* orow = O + (size_t)(row0 + 1) * kD + 8 * r;
            float4 o0, o1;
            o0.x = a10.x * inv; o0.y = a10.y * inv; o0.z = a10.z * inv; o0.w = a10.w * inv;
            o1.x = a11.x * inv; o1.y = a11.y * inv; o1.z = a11.z * inv; o1.w = a11.w * inv;
            *reinterpret_cast<float4*>(orow)     = o0;
            *reinterpret_cast<float4*>(orow + 4) = o1;
        }
        return;
    }

    // -------- generic fallback (not hit by the bench mask): per query --------
    #pragma unroll 1
    for (int qq = 0; qq < 2; ++qq) {
        const int t  = t0 + qq;
        const int qm = mb[t];
        const float4 q0 = qq ? qb0 : qa0;
        const float4 q1 = qq ? qb1 : qa1;
        int lo, hi;
        if (qm) {
            lo = t - kBand; if (lo < 0) lo = 0;
            hi = t + kBand; if (hi > kT - 1) hi = kT - 1;
        } else {
            lo = 0; hi = kT - 1;
        }
        float m = -INFINITY, l = 0.f;
        float4 acc0 = make_float4(0.f,0.f,0.f,0.f), acc1 = acc0;
        for (int s = lo + g; s <= hi; s += 8) {
            const float* kr = kb + (size_t)s * kD + 8 * r;
            const float4 k0 = *reinterpret_cast<const float4*>(kr);
            const float4 k1 = *reinterpret_cast<const float4*>(kr + 4);
            float d = q0.x * k0.x + q0.y * k0.y + q0.z * k0.z + q0.w * k0.w
                    + q1.x * k1.x + q1.y * k1.y + q1.z * k1.z + q1.w * k1.w;
            d = sum8_dpp(d);
            if (mb[s]) {
                const float mn  = fmaxf(m, d);
                const float scl = __expf(m - mn);
                const float w   = __expf(d - mn);
                const float* vr = vb + (size_t)s * kD + 8 * r;
                const float4 v0 = *reinterpret_cast<const float4*>(vr);
                const float4 v1 = *reinterpret_cast<const float4*>(vr + 4);
                l = l * scl + w;
                acc0.x = acc0.x * scl + w * v0.x; acc0.y = acc0.y * scl + w * v0.y;
                acc0.z = acc0.z * scl + w * v0.z; acc0.w = acc0.w * scl + w * v0.w;
                acc1.x = acc1.x * scl + w * v1.x; acc1.y = acc1.y * scl + w * v1.y;
                acc1.z = acc1.z * scl + w * v1.z; acc1.w = acc1.w * scl + w * v1.w;
                m = mn;
            }
        }
        #pragma unroll
        for (int off = 8; off <= 32; off <<= 1) {
            const float m2 = __shfl_xor(m, off, 64);
            const float l2 = __shfl_xor(l, off, 64);
            float4 b0, b1;
            b0.x = __shfl_xor(acc0.x, off, 64); b0.y = __shfl_xor(acc0.y, off, 64);
            b0.z = __shfl_xor(acc0.z, off, 64); b0.w = __shfl_xor(acc0.w, off, 64);
            b1.x = __shfl_xor(acc1.x, off, 64); b1.y = __shfl_xor(acc1.y, off, 64);
            b1.z = __shfl_xor(acc1.z, off, 64); b1.w = __shfl_xor(acc1.w, off, 64);
            const float mm = fmaxf(m, m2);
            const float e1 = (m  == -INFINITY) ? 0.f : __expf(m  - mm);
            const float e2 = (m2 == -INFINITY) ? 0.f : __expf(m2 - mm);
            l = l * e1 + l2 * e2;
            acc0.x = acc0.x * e1 + b0.x * e2; acc0.y = acc0.y * e1 + b0.y * e2;
            acc0.z = acc0.z * e1 + b0.z * e2; acc0.w = acc0.w * e1 + b0.w * e2;
            acc1.x = acc1.x * e1 + b1.x * e2; acc1.y = acc1.y * e1 + b1.y * e2;
            acc1.z = acc1.z * e1 + b1.z * e2; acc1.w = acc1.w * e1 + b1.w * e2;
            m = mm;
        }
        if (g == 0) {
            const float inv = 1.0f / l;
            float* orow = O + (size_t)(b * kT + t) * kD + 8 * r;
            float4 o0, o1;
            o0.x = acc0.x * inv; o0.y = acc0.y * inv;
            o0.z = acc0.z * inv; o0.w = acc0.w * inv;
            o1.x = acc1.x * inv; o1.y = acc1.y * inv;
            o1.z = acc1.z * inv; o1.w = acc1.w * inv;
            *reinterpret_cast<float4*>(orow)     = o0;
            *reinterpret_cast<float4*>(orow + 4) = o1;
        }
    }
}

extern "C" void kernel_launch(void* const* d_in, const int* in_sizes, int n_in,
                              void* d_out, int out_size, void* d_ws, size_t ws_size,
                              hipStream_t stream) {
    const float* q    = (const float*)d_in[0];
    const float* k    = (const float*)d_in[1];
    const float* v    = (const float*)d_in[2];
    const int*   mask = (const int*)d_in[3];
    float*       out  = (float*)d_out;

    const int pairs = (kB * kT) / 2;          // 8192 query pairs
    dim3 grid(pairs / 4);                     // 4 waves (pairs) per block
    dim3 block(256);
    band_attn_kernel<<<grid, block, 0, stream>>>(q, k, v, mask, out);
}